// Round 3
// baseline (15509.415 us; speedup 1.0000x reference)
//
#include <hip/hip_runtime.h>
#include <hip/hip_bf16.h>
#include <hip/hip_fp16.h>

typedef __attribute__((ext_vector_type(4))) float f32x4;
typedef _Float16 f16;
typedef __attribute__((ext_vector_type(4))) _Float16 f16x4;
typedef __attribute__((ext_vector_type(8))) _Float16 f16x8;

#define DEV static __device__ __forceinline__

constexpr int B_ = 128, T_ = 2048, H_ = 256, TRG_ = 24;
constexpr int NBLK = 8;   // encoder blocks, 16 batches each

// ---------------- workspace layout (total ~150.4 MiB) ----------------
constexpr size_t XF_OFF   = 0;                                   // x A-fragments [t][blk][bb][32] f16
constexpr size_t XF_BYTES = (size_t)T_ * NBLK * 16 * 32 * 2;     // 16 MiB
constexpr size_t OUTS_OFF = XF_OFF + XF_BYTES;
constexpr size_t OUTS_BYTES = (size_t)B_ * T_ * H_ * 2;          // 128 MiB f16
constexpr size_t EPROJ_OFF = OUTS_OFF + OUTS_BYTES;
constexpr size_t EPROJ_BYTES = (size_t)B_ * T_ * 4;              // 1 MiB
constexpr size_t HH_OFF = EPROJ_OFF + EPROJ_BYTES;               // ping-pong decoder h (buf0 = enc final)
constexpr size_t HH_BYTES = 2ull * B_ * H_ * 4;
constexpr size_t CC_OFF = HH_OFF + HH_BYTES;
constexpr size_t CC_BYTES = (size_t)B_ * H_ * 4;
constexpr size_t WXD_OFF = CC_OFF + CC_BYTES;                    // Wih_d[:,1:] @ Wfc  (1024x256) f32
constexpr size_t WXD_BYTES = 1024ull * 256 * 4;
constexpr size_t VV_OFF = WXD_OFF + WXD_BYTES;                   // v[256] v2[256] c0 c2 ... bdp[1024]@576
constexpr size_t VV_BYTES = 8192;
constexpr size_t WS67_OFF = VV_OFF + VV_BYTES;                   // streamed enc weights ks6,7 (x2 copies)
constexpr size_t WS67_BYTES = 2ull * 2 * 64 * 64 * 16;           // 256 KiB
constexpr size_t XB_OFF = WS67_OFF + WS67_BYTES;                 // streamed x weights (x2 copies)
constexpr size_t XB_BYTES = 2ull * 64 * 64 * 16;                 // 128 KiB
constexpr size_t ZERO_OFF = XB_OFF + XB_BYTES;
constexpr size_t CTX_CNT = 24ull * 128 * 257;   // ctxacc
constexpr size_t SAC_CNT = 25ull * 128;         // s_acc
constexpr size_t PRD_CNT = 24ull * 128;         // pred_acc
constexpr size_t INP_CNT = 25ull * 128;         // inp_buf
constexpr size_t ZERO_CNT = CTX_CNT + SAC_CNT + PRD_CNT + INP_CNT;
constexpr size_t DUMP_OFF = ((ZERO_OFF + ZERO_CNT * 4 + 255) & ~(size_t)255);
constexpr size_t DUMP_ONE = (size_t)B_ * H_ * 4;                 // 128 KiB each
// dumps: cdump (c_2046), ccfin (c_2047), hfin (h_2047), h1d (h after d=0)
constexpr size_t WS_NEED = DUMP_OFF + 4 * DUMP_ONE + 1024;

// ---------------- helpers ----------------
DEV float sigf(float x)  { return 1.0f / (1.0f + __expf(-x)); }
DEV float tanh_(float x) { return 1.0f - 2.0f / (__expf(2.0f * x) + 1.0f); }

// ---------------- ws-too-small sentinel: absmax reports ws MiB ----------------
__global__ void k_wsfail(float* __restrict__ dout, float mb) { dout[0] = 1e6f + mb; }

// ---------------- zero scratch ----------------
__global__ void k_zero(float* __restrict__ p, size_t n) {
  size_t i = (size_t)blockIdx.x * blockDim.x + threadIdx.x;
  size_t s = (size_t)gridDim.x * blockDim.x;
  for (; i < n; i += s) p[i] = 0.f;
}

// ---------------- small precomputed vectors ----------------
// vv: [0,256) v = Wfc.T@Wa_e ; [256,512) v2 = Wfc.T@Wf2 ; [512] c0=bfc.Wa_e ; [513] c2=bfc.Wf2+bf2 ;
// [576,1600) bdp = bih_d+bhh_d + Wih_d[:,1:]@bfc
__global__ void k_prep(const float* __restrict__ Wfc, const float* __restrict__ Wa,
                       const float* __restrict__ Wf2, const float* __restrict__ bf2_,
                       const float* __restrict__ bfc, const float* __restrict__ bihd,
                       const float* __restrict__ bhhd, const float* __restrict__ Wihd,
                       float* __restrict__ vv) {
  const int blk = blockIdx.x, tid = threadIdx.x;
  if (blk == 0) {
    float a = 0; for (int h = 0; h < 256; ++h) a += Wfc[h * 256 + tid] * Wa[256 + h];
    vv[tid] = a;
  } else if (blk == 1) {
    float a = 0; for (int h = 0; h < 256; ++h) a += Wfc[h * 256 + tid] * Wf2[h];
    vv[256 + tid] = a;
  } else if (blk == 2) {
    if (tid == 0) { float a = 0; for (int h = 0; h < 256; ++h) a += bfc[h] * Wa[256 + h]; vv[512] = a; }
    if (tid == 1) { float a = bf2_[0]; for (int h = 0; h < 256; ++h) a += bfc[h] * Wf2[h]; vv[513] = a; }
  } else if (blk < 7) {
    int j = (blk - 3) * 256 + tid;
    float a = bihd[j] + bhhd[j];
    for (int h = 0; h < 256; ++h) a += Wihd[j * 257 + 1 + h] * bfc[h];
    vv[576 + j] = a;
  }
}

// Wxd[j][k] = sum_h Wih_d[j][1+h] * Wfc[h][k]
__global__ void k_wxd(const float* __restrict__ Wihd, const float* __restrict__ Wfc,
                      float* __restrict__ wxd) {
  const int j = blockIdx.x, k = threadIdx.x;
  __shared__ float sR[256];
  sR[k] = Wihd[j * 257 + 1 + k];
  __syncthreads();
  float a = 0;
  for (int h = 0; h < 256; ++h) a += sR[h] * Wfc[h * 256 + k];
  wxd[j * 256 + k] = a;
}

// ---------------- streamed encoder weight images (f16, MFMA B-fragment order) ----------------
// ws67: [copy][ks-6][fragf=(w*2+p)*4+q][lane] x f16x8 ; xb: [copy][fragf][lane] x f16x8
// xb row content: k<15: Wih[j][k] (src1), k==15: Wih[j][15] (sm), k==16: bih+bhh (bias), else 0
__global__ void k_wprep(const float* __restrict__ Whh, const float* __restrict__ Wih,
                        const float* __restrict__ bih, const float* __restrict__ bhh,
                        f16* __restrict__ ws67, f16* __restrict__ xb) {
  int i = blockIdx.x * 256 + threadIdx.x;
  if (i < 16384) {
    int l = i & 63, f = (i >> 6) & 63, ks2 = (i >> 12) & 1;
    int q = f & 3, p = (f >> 2) & 1, w = f >> 3;
    int g = l >> 4, c16 = l & 15;
    int row = 256 * q + 16 * (w + 8 * p) + c16;
    f16x8 v;
#pragma unroll
    for (int jj = 0; jj < 8; ++jj) v[jj] = (f16)Whh[row * 256 + (6 + ks2) * 32 + 8 * g + jj];
    ((f16x8*)ws67)[i] = v;
  } else {
    int j = i - 16384;
    int l = j & 63, f = (j >> 6) & 63;
    int q = f & 3, p = (f >> 2) & 1, w = f >> 3;
    int g = l >> 4, c16 = l & 15;
    int row = 256 * q + 16 * (w + 8 * p) + c16;
    f16x8 v;
#pragma unroll
    for (int jj = 0; jj < 8; ++jj) {
      int k = 8 * g + jj;
      float val = (k < 16) ? Wih[row * 16 + k] : (k == 16 ? (bih[row] + bhh[row]) : 0.f);
      v[jj] = (f16)val;
    }
    ((f16x8*)xb)[j] = v;
  }
}

// ---------------- x A-fragment prepass: xf[t*128+b][32] = [src1(15), sm, 1, 0...] f16 ----------
__global__ __launch_bounds__(256) void k_xf(const float* __restrict__ src1,
    const float* __restrict__ src2, const float* __restrict__ Wc, const float* __restrict__ bc,
    f16* __restrict__ xf) {
  int i = blockIdx.x * 256 + threadIdx.x;   // i = t*128 + b
  int t = i >> 7, b = i & 127;
  f16x8 v0, v1, v2, v3;
#pragma unroll
  for (int f = 0; f < 8; ++f)  v0[f] = (f16)src1[((size_t)b * T_ + t) * 15 + f];
#pragma unroll
  for (int f = 0; f < 7; ++f)  v1[f] = (f16)src1[((size_t)b * T_ + t) * 15 + 8 + f];
  float s = bc[0];
#pragma unroll
  for (int u = 0; u < 8; ++u) s += src2[((size_t)b * T_ + t) * 8 + u] * Wc[u];
  v1[7] = (f16)s;
  v2 = (f16x8){(f16)1.f, (f16)0.f, (f16)0.f, (f16)0.f, (f16)0.f, (f16)0.f, (f16)0.f, (f16)0.f};
  v3 = (f16x8){(f16)0.f, (f16)0.f, (f16)0.f, (f16)0.f, (f16)0.f, (f16)0.f, (f16)0.f, (f16)0.f};
  f16* o = xf + (size_t)i * 32;
  *(f16x8*)(o) = v0; *(f16x8*)(o + 8) = v1; *(f16x8*)(o + 16) = v2; *(f16x8*)(o + 24) = v3;
}

// ---------------- encoder: persistent, fp16 MFMA; ks0-3 VGPR, ks4-5 LDS, ks6-7+x streamed ------
__global__ __launch_bounds__(512) void k_enc(const float* __restrict__ Whh,
    const f16* __restrict__ ws67, const f16* __restrict__ xb, const f16* __restrict__ xf,
    f16* __restrict__ outs, float* __restrict__ hh0, float* __restrict__ cc0,
    float* __restrict__ cdump, float* __restrict__ hfin, float* __restrict__ ccfin) {
  const int blk = blockIdx.x, tid = threadIdx.x;
  const int w = tid >> 6, l = tid & 63, g = l >> 4, c16 = l & 15;
  __shared__ f16x8 Wl[8192];        // ks4,5 B-fragments: [(ksl*8+w)*2+p)*4+q][lane]  = 128 KiB
  __shared__ f16 hbuf[16 * 260];    // h[b][jh], padded stride 260 (conflict-free b64 reads)

  // VGPR-resident weights ks0..3 (per-lane exact B-fragment slices)
  f16x8 wf[4][2][4];
#pragma unroll
  for (int ks = 0; ks < 4; ++ks)
#pragma unroll
    for (int p = 0; p < 2; ++p)
#pragma unroll
      for (int q = 0; q < 4; ++q) {
        const int row = 256 * q + 16 * (w + 8 * p) + c16;
        const float* s = Whh + row * 256 + ks * 32 + 8 * g;
        f16x8 v;
#pragma unroll
        for (int jj = 0; jj < 8; ++jj) v[jj] = (f16)s[jj];
        wf[ks][p][q] = v;
      }
  // LDS-resident weights ks4,5
#pragma unroll
  for (int ksl = 0; ksl < 2; ++ksl)
#pragma unroll
    for (int p = 0; p < 2; ++p)
#pragma unroll
      for (int q = 0; q < 4; ++q) {
        const int row = 256 * q + 16 * (w + 8 * p) + c16;
        const float* s = Whh + row * 256 + (4 + ksl) * 32 + 8 * g;
        f16x8 v;
#pragma unroll
        for (int jj = 0; jj < 8; ++jj) v[jj] = (f16)s[jj];
        Wl[((((ksl * 8 + w) * 2 + p) * 4 + q)) * 64 + l] = v;
      }
  for (int i = tid; i < 16 * 260; i += 512) hbuf[i] = (f16)0.f;
  __syncthreads();

  f32x4 cst[2];
  cst[0] = (f32x4){0.f, 0.f, 0.f, 0.f};
  cst[1] = (f32x4){0.f, 0.f, 0.f, 0.f};

  const int fq = (w * 2 + 0) * 4;   // fragment index base helper (w,p,q) = (w*2+p)*4+q

  for (int t = 0; t < T_; ++t) {
    const int cp = t & 1;           // alternate stream copies (defeats load hoisting)
    const f16x8* s6 = (const f16x8*)ws67 + ((size_t)(cp * 2 + 0) * 64) * 64;
    const f16x8* s7 = (const f16x8*)ws67 + ((size_t)(cp * 2 + 1) * 64) * 64;
    const f16x8* sx = (const f16x8*)xb + (size_t)cp * 64 * 64;

    // issue group 1: ks6 B + x A
    f16x8 b6[2][4];
#pragma unroll
    for (int p = 0; p < 2; ++p)
#pragma unroll
      for (int q = 0; q < 4; ++q) b6[p][q] = s6[(size_t)(fq + p * 4 + q) * 64 + l];
    const f16x8 xa = *(const f16x8*)(xf + (((size_t)t * 8 + blk) * 16 + c16) * 32 + 8 * g);

    f32x4 acc[2][4];
#pragma unroll
    for (int p = 0; p < 2; ++p)
#pragma unroll
      for (int q = 0; q < 4; ++q) acc[p][q] = (f32x4){0.f, 0.f, 0.f, 0.f};

    // h A-fragment reader: h[batch=c16][k = ks*32 + 8g + 0..7]
#define LDA(ks) ({ const f16* hp = hbuf + c16 * 260 + (ks) * 32 + 8 * g; \
                   f16x4 a0 = *(const f16x4*)hp; f16x4 a1 = *(const f16x4*)(hp + 4); \
                   f16x8 a; a[0]=a0[0];a[1]=a0[1];a[2]=a0[2];a[3]=a0[3]; \
                   a[4]=a1[0];a[5]=a1[1];a[6]=a1[2];a[7]=a1[3]; a; })

    // ks0..3 from VGPR
#pragma unroll
    for (int ks = 0; ks < 4; ++ks) {
      const f16x8 a = LDA(ks);
#pragma unroll
      for (int p = 0; p < 2; ++p)
#pragma unroll
        for (int q = 0; q < 4; ++q)
          acc[p][q] = __builtin_amdgcn_mfma_f32_16x16x32_f16(a, wf[ks][p][q], acc[p][q], 0, 0, 0);
    }
    // consume ks6 (streamed), then issue ks7
    {
      const f16x8 a = LDA(6);
#pragma unroll
      for (int p = 0; p < 2; ++p)
#pragma unroll
        for (int q = 0; q < 4; ++q)
          acc[p][q] = __builtin_amdgcn_mfma_f32_16x16x32_f16(a, b6[p][q], acc[p][q], 0, 0, 0);
    }
    f16x8 b7[2][4];
#pragma unroll
    for (int p = 0; p < 2; ++p)
#pragma unroll
      for (int q = 0; q < 4; ++q) b7[p][q] = s7[(size_t)(fq + p * 4 + q) * 64 + l];
    // ks4 from LDS
    {
      const f16x8 a = LDA(4);
#pragma unroll
      for (int p = 0; p < 2; ++p)
#pragma unroll
        for (int q = 0; q < 4; ++q) {
          const f16x8 bb = Wl[(((0 * 8 + w) * 2 + p) * 4 + q) * 64 + l];
          acc[p][q] = __builtin_amdgcn_mfma_f32_16x16x32_f16(a, bb, acc[p][q], 0, 0, 0);
        }
    }
    // issue x B
    f16x8 bx[2][4];
#pragma unroll
    for (int p = 0; p < 2; ++p)
#pragma unroll
      for (int q = 0; q < 4; ++q) bx[p][q] = sx[(size_t)(fq + p * 4 + q) * 64 + l];
    // ks5 from LDS
    {
      const f16x8 a = LDA(5);
#pragma unroll
      for (int p = 0; p < 2; ++p)
#pragma unroll
        for (int q = 0; q < 4; ++q) {
          const f16x8 bb = Wl[(((1 * 8 + w) * 2 + p) * 4 + q) * 64 + l];
          acc[p][q] = __builtin_amdgcn_mfma_f32_16x16x32_f16(a, bb, acc[p][q], 0, 0, 0);
        }
    }
    // consume ks7 (streamed)
    {
      const f16x8 a = LDA(7);
#pragma unroll
      for (int p = 0; p < 2; ++p)
#pragma unroll
        for (int q = 0; q < 4; ++q)
          acc[p][q] = __builtin_amdgcn_mfma_f32_16x16x32_f16(a, b7[p][q], acc[p][q], 0, 0, 0);
    }
    // x part (+bias via feature k=16)
#pragma unroll
    for (int p = 0; p < 2; ++p)
#pragma unroll
      for (int q = 0; q < 4; ++q)
        acc[p][q] = __builtin_amdgcn_mfma_f32_16x16x32_f16(xa, bx[p][q], acc[p][q], 0, 0, 0);
#undef LDA

    __syncthreads();   // all hbuf reads done before rewrite
#pragma unroll
    for (int p = 0; p < 2; ++p) {
      const int jh = 16 * (w + 8 * p) + c16;
#pragma unroll
      for (int r = 0; r < 4; ++r) {
        const float iv = acc[p][0][r], fv = acc[p][1][r], gv = acc[p][2][r], ov = acc[p][3][r];
        const float cn = sigf(fv) * cst[p][r] + sigf(iv) * tanh_(gv);
        cst[p][r] = cn;
        const float hn = sigf(ov) * tanh_(cn);
        const int bl = 4 * g + r;
        hbuf[bl * 260 + jh] = (f16)hn;
        outs[((size_t)(blk * 16 + bl) * T_ + t) * H_ + jh] = (f16)hn;
        if (t == 2046) cdump[(blk * 16 + bl) * H_ + jh] = cn;
        if (t == T_ - 1) {
          hh0[(blk * 16 + bl) * H_ + jh] = hn;
          cc0[(blk * 16 + bl) * H_ + jh] = cn;
          hfin[(blk * 16 + bl) * H_ + jh] = hn;
          ccfin[(blk * 16 + bl) * H_ + jh] = cn;
        }
      }
    }
    __syncthreads();
  }
}

// ---------------- eproj = outs.v + c0 ----------------
__global__ void k_eproj(const f16* __restrict__ outs, const float* __restrict__ vv,
                        float* __restrict__ eproj) {
  __shared__ float sv[256];
  const int tid = threadIdx.x;
  sv[tid] = vv[tid];
  __syncthreads();
  const int wv = tid >> 6, l = tid & 63;
  const int flat = blockIdx.x * 4 + wv;     // b*T + t
  const f16* op = outs + (size_t)flat * H_ + l * 4;
  float sum = 0;
#pragma unroll
  for (int i = 0; i < 4; ++i) sum += (float)op[i] * sv[l * 4 + i];
  for (int off = 32; off > 0; off >>= 1) sum += __shfl_down(sum, off);
  if (l == 0) eproj[flat] = sum + vv[512];
}

// ---------------- decoder init: token + s0 ----------------
__global__ void k_decinit(const f16* __restrict__ outs, const float* __restrict__ hh,
                          const float* __restrict__ Wa, const float* __restrict__ vv,
                          float* __restrict__ inp_buf, float* __restrict__ s_acc) {
  int b = threadIdx.x;
  if (b >= B_) return;
  float tok = vv[513];
  const f16* op = outs + ((size_t)b * T_ + (T_ - 1)) * H_;
  for (int k = 0; k < H_; ++k) tok += (float)op[k] * vv[256 + k];
  float s0 = 0;
  for (int j = 0; j < H_; ++j) s0 += hh[b * H_ + j] * Wa[j];
  inp_buf[b] = tok;
  s_acc[b] = s0;
}

// ---------------- attention: ctx' = softmax(tanh(s+eproj)) @ outs ----------------
__global__ void k_attn(int d, const float* __restrict__ eproj, const f16* __restrict__ outs,
                       const float* __restrict__ s_acc, float* __restrict__ ctxacc,
                       const float* __restrict__ pred_acc, float* __restrict__ inp_buf,
                       float* __restrict__ dout, const float* __restrict__ bo) {
  const int b = blockIdx.x >> 4, ch = blockIdx.x & 15;
  const int k = threadIdx.x;
  if (d > 0 && ch == 0 && k == 0) {   // finalize previous step's prediction
    float pv = pred_acc[(d - 1) * B_ + b] + bo[0];
    inp_buf[d * B_ + b] = pv;
    dout[b * TRG_ + (d - 1)] = pv;
  }
  __shared__ float swt[128];
  const float s = s_acc[d * B_ + b];
  if (k < 128) {
    float e = eproj[b * T_ + ch * 128 + k];
    swt[k] = __expf(tanh_(s + e));   // tanh bounds energies -> exp safe without max-subtract
  }
  __syncthreads();
  float acc = 0.f;
  const f16* op = outs + ((size_t)b * T_ + ch * 128) * H_ + k;
#pragma unroll 4
  for (int tt = 0; tt < 128; ++tt) acc += swt[tt] * (float)op[tt * H_];
  atomicAdd(&ctxacc[((size_t)d * B_ + b) * 257 + k], acc);
  if (k == 0) {
    float sw = 0;
    for (int tt = 0; tt < 128; ++tt) sw += swt[tt];
    atomicAdd(&ctxacc[((size_t)d * B_ + b) * 257 + 256], sw);
  }
}

// ---------------- decoder LSTM cell (+ next s, pred partials) ----------------
__global__ __launch_bounds__(512) void k_cell(int d, const float* __restrict__ wxd,
    const float* __restrict__ Whhd, const float* __restrict__ Wihd, const float* __restrict__ vv,
    const float* __restrict__ ctxacc, const float* __restrict__ inp_buf,
    float* __restrict__ hh, float* __restrict__ cc,
    float* __restrict__ s_acc, float* __restrict__ pred_acc,
    const float* __restrict__ Wa, const float* __restrict__ Wo) {
  const int jb = blockIdx.x;               // hidden cols [4jb, 4jb+4)
  const int tid = threadIdx.x;
  const int rr = tid & 15, bb = tid >> 4;  // rr = gate*4+jsub, bb = 0..31
  __shared__ float sW[16][516];
  __shared__ float sX[32][516];
  __shared__ float sG[32][17];
  __shared__ float sden[32], sinp[32];
  __shared__ float scol0[16], sbias[16];
  const float* bdp = vv + 576;
  for (int idx = tid; idx < 16 * 512; idx += 512) {
    int r2 = idx >> 9, k2 = idx & 511;
    int row = 256 * (r2 >> 2) + 4 * jb + (r2 & 3);
    sW[r2][k2] = (k2 < 256) ? wxd[row * 256 + k2] : Whhd[row * 256 + (k2 - 256)];
  }
  if (tid < 16) {
    int row = 256 * (tid >> 2) + 4 * jb + (tid & 3);
    scol0[tid] = Wihd[row * 257];
    sbias[tid] = bdp[row];
  }
  const float* hh_r = hh + (d & 1) * B_ * H_;
  float* hh_w = hh + ((d + 1) & 1) * B_ * H_;
  for (int bc = 0; bc < 4; ++bc) {
    __syncthreads();
    if (tid < 32) {
      int b = bc * 32 + tid;
      sden[tid] = 1.0f / ctxacc[((size_t)d * B_ + b) * 257 + 256];
      sinp[tid] = inp_buf[d * B_ + b];
    }
    __syncthreads();
    for (int idx = tid; idx < 32 * 512; idx += 512) {
      int b2 = idx >> 9, k2 = idx & 511;
      int b = bc * 32 + b2;
      sX[b2][k2] = (k2 < 256) ? ctxacc[((size_t)d * B_ + b) * 257 + k2] * sden[b2]
                              : hh_r[b * 256 + (k2 - 256)];
    }
    __syncthreads();
    {
      float a = sbias[rr] + scol0[rr] * sinp[bb];
      const float* wr = sW[rr];
      const float* xr = sX[bb];
      for (int k4 = 0; k4 < 512; k4 += 4)
        a += wr[k4] * xr[k4] + wr[k4 + 1] * xr[k4 + 1] + wr[k4 + 2] * xr[k4 + 2] + wr[k4 + 3] * xr[k4 + 3];
      sG[bb][rr] = a;
    }
    __syncthreads();
    if (rr < 4) {
      int b = bc * 32 + bb;
      int jh = 4 * jb + rr;
      float iv = sG[bb][rr], fv = sG[bb][4 + rr], gv = sG[bb][8 + rr], ov = sG[bb][12 + rr];
      float cn = sigf(fv) * cc[b * H_ + jh] + sigf(iv) * tanh_(gv);
      cc[b * H_ + jh] = cn;
      float hn = sigf(ov) * tanh_(cn);
      hh_w[b * H_ + jh] = hn;
      atomicAdd(&s_acc[(d + 1) * B_ + b], hn * Wa[jh]);
      atomicAdd(&pred_acc[d * B_ + b], hn * Wo[jh]);
    }
  }
}

__global__ void k_finish(const float* __restrict__ pred_acc, const float* __restrict__ bo,
                         float* __restrict__ dout) {
  int b = threadIdx.x;
  if (b < B_) dout[b * TRG_ + (TRG_ - 1)] = pred_acc[(TRG_ - 1) * B_ + b] + bo[0];
}

__global__ void k_copyh(const float* __restrict__ src, float* __restrict__ dst) {
  dst[blockIdx.x * 512 + threadIdx.x] = src[blockIdx.x * 512 + threadIdx.x];
}

// =================== SELF-CHECK KERNELS (diagnosis sentinels) ===================
// Sentinel map: dout[0]=1e9 encoder; dout[1]=1e6 prep/wxd/eproj; dout[2]=4e3 ctx / 3e4 token
//               / 1e3 chain+pred; dout[3]=2e3 decoder cell. (ws-fail: 1e6+MiB)

__global__ void k_check_enc(const float* __restrict__ src1, const float* __restrict__ src2,
    const float* __restrict__ Wc, const float* __restrict__ bc, const float* __restrict__ Wih,
    const float* __restrict__ bih, const float* __restrict__ bhh, const float* __restrict__ Whh,
    const f16* __restrict__ outs, const float* __restrict__ cdump,
    const float* __restrict__ hfin, const float* __restrict__ ccfin, float* __restrict__ dout) {
  const int b = blockIdx.x & 127, jh = threadIdx.x;
  const int late = blockIdx.x >> 7;
  const int t = late ? (T_ - 1) : 0;
  float x[16];
  for (int f = 0; f < 15; ++f) x[f] = src1[((size_t)b * T_ + t) * 15 + f];
  {
    float s = bc[0];
    for (int u = 0; u < 8; ++u) s += src2[((size_t)b * T_ + t) * 8 + u] * Wc[u];
    x[15] = s;
  }
  float gg[4];
  for (int gt = 0; gt < 4; ++gt) {
    int row = gt * 256 + jh;
    float a = bih[row] + bhh[row];
    for (int f = 0; f < 16; ++f) a += x[f] * Wih[row * 16 + f];
    if (late)
      for (int k = 0; k < 256; ++k)
        a += (float)outs[((size_t)b * T_ + (T_ - 2)) * H_ + k] * Whh[row * 256 + k];
    gg[gt] = a;
  }
  float cp = late ? cdump[b * H_ + jh] : 0.f;
  float cn = sigf(gg[1]) * cp + sigf(gg[0]) * tanh_(gg[2]);
  float hn = sigf(gg[3]) * tanh_(cn);
  float hs = (float)outs[((size_t)b * T_ + t) * H_ + jh];
  bool bad = fabsf(hn - hs) > 3e-3f;
  if (late) {
    bad = bad || fabsf(hn - hfin[b * H_ + jh]) > 3e-3f
              || fabsf(cn - ccfin[b * H_ + jh]) > 5e-3f;
  }
  if (bad) dout[0] = 1e9f;
}

__global__ void k_check_mid(const float* __restrict__ Wfc, const float* __restrict__ Wa,
    const float* __restrict__ Wf2, const float* __restrict__ bf2_, const float* __restrict__ bfc,
    const float* __restrict__ bihd, const float* __restrict__ bhhd, const float* __restrict__ Wihd,
    const float* __restrict__ vv, const float* __restrict__ wxd, const f16* __restrict__ outs,
    const float* __restrict__ eproj, float* __restrict__ dout) {
  const int blk = blockIdx.x, tid = threadIdx.x;
  bool bad = false;
  if (blk == 0) {
    float a = 0, a2 = 0;
    for (int h = 0; h < 256; ++h) { a += Wfc[h * 256 + tid] * Wa[256 + h]; a2 += Wfc[h * 256 + tid] * Wf2[h]; }
    bad = fabsf(a - vv[tid]) > 1e-4f || fabsf(a2 - vv[256 + tid]) > 1e-4f;
    if (tid == 0) { float c = 0; for (int h = 0; h < 256; ++h) c += bfc[h] * Wa[256 + h]; bad = bad || fabsf(c - vv[512]) > 1e-4f; }
    if (tid == 1) { float c = bf2_[0]; for (int h = 0; h < 256; ++h) c += bfc[h] * Wf2[h]; bad = bad || fabsf(c - vv[513]) > 1e-4f; }
  } else if (blk < 5) {
    int j = (blk - 1) * 256 + tid;
    float a = bihd[j] + bhhd[j];
    for (int h = 0; h < 256; ++h) a += Wihd[j * 257 + 1 + h] * bfc[h];
    bad = fabsf(a - vv[576 + j]) > 1e-4f;
  } else if (blk < 69) {
    int j = (blk - 5) * 16 + (tid >> 4);
    int k = (tid & 15) * 17;
    float a = 0;
    for (int h = 0; h < 256; ++h) a += Wihd[j * 257 + 1 + h] * Wfc[h * 256 + k];
    bad = fabsf(a - wxd[j * 256 + k]) > 1e-4f;
  } else {
    int b = blk - 69;        // 128 blocks
    int t = tid * 8 + 3;
    float s = vv[512];
    const f16* op = outs + ((size_t)b * T_ + t) * H_;
    for (int k = 0; k < 256; ++k) s += (float)op[k] * vv[k];
    bad = fabsf(s - eproj[b * T_ + t]) > 1e-3f;
  }
  if (bad) dout[1] = 1e6f;
}

__global__ void k_check_dec(const f16* __restrict__ outs, const float* __restrict__ eproj,
    const float* __restrict__ s_acc, const float* __restrict__ ctxacc,
    const float* __restrict__ inp_buf, const float* __restrict__ hh,
    const float* __restrict__ hfin, const float* __restrict__ h1d,
    const float* __restrict__ Wa, const float* __restrict__ Wo, const float* __restrict__ bo,
    const float* __restrict__ vv, float* __restrict__ dout) {
  const int b = blockIdx.x, tid = threadIdx.x;
  bool bad = false; float sent = 4e3f;
  const float s0 = s_acc[b];
  if (tid < 32) {                 // ctx component k (d=0)
    int k = tid * 8 + 1;
    double a = 0;
    for (int t = 0; t < T_; ++t)
      a += (double)(__expf(tanh_(s0 + eproj[b * T_ + t])) * (float)outs[((size_t)b * T_ + t) * H_ + k]);
    float af = (float)a;
    bad = fabsf(af - ctxacc[(size_t)b * 257 + k]) > 0.05f * fmaxf(1.f, fabsf(af));
  } else if (tid == 33) {         // denominator (d=0)
    double a = 0;
    for (int t = 0; t < T_; ++t) a += (double)__expf(tanh_(s0 + eproj[b * T_ + t]));
    bad = fabsf((float)a - ctxacc[(size_t)b * 257 + 256]) > 0.3f;
  } else if (tid == 34) {         // s_acc[1] from h after d=0
    float a = 0;
    for (int j = 0; j < 256; ++j) a += h1d[b * 256 + j] * Wa[j];
    bad = fabsf(a - s_acc[B_ + b]) > 1e-3f;
  } else if (tid == 35) {         // s0 from enc-final h
    float a = 0;
    for (int j = 0; j < 256; ++j) a += hfin[b * 256 + j] * Wa[j];
    bad = fabsf(a - s0) > 1e-3f;
  } else if (tid == 36) {         // token
    float a = vv[513];
    for (int k = 0; k < 256; ++k) a += (float)outs[((size_t)b * T_ + (T_ - 1)) * H_ + k] * vv[256 + k];
    bad = fabsf(a - inp_buf[b]) > 1e-3f; sent = 3e4f;
  } else if (tid >= 37 && tid < 60) {  // inp chain d=1..23 (exact copies)
    int d = tid - 36;
    bad = fabsf(inp_buf[d * B_ + b] - dout[b * TRG_ + (d - 1)]) > 1e-5f; sent = 1e3f;
  } else if (tid == 60) {         // pred0 from h1d
    float a = bo[0];
    for (int j = 0; j < 256; ++j) a += h1d[b * 256 + j] * Wo[j];
    bad = fabsf(a - dout[b * TRG_ + 0]) > 2e-4f; sent = 1e3f;
  } else if (tid == 61) {         // pred23 from hh buf0 (= h after d=23)
    float a = bo[0];
    for (int j = 0; j < 256; ++j) a += hh[b * 256 + j] * Wo[j];
    bad = fabsf(a - dout[b * TRG_ + 23]) > 2e-4f; sent = 1e3f;
  }
  if (bad) dout[2] = sent;
}

__global__ void k_check_cell(const float* __restrict__ wxd, const float* __restrict__ Whhd,
    const float* __restrict__ Wihd, const float* __restrict__ vv, const float* __restrict__ ctxacc,
    const float* __restrict__ inp_buf, const float* __restrict__ hfin, const float* __restrict__ ccfin,
    const float* __restrict__ h1d, float* __restrict__ dout) {
  const int b = blockIdx.x, jh = threadIdx.x;
  const float den = 1.0f / ctxacc[(size_t)b * 257 + 256];
  const float inp = inp_buf[b];
  float gg[4];
  for (int gt = 0; gt < 4; ++gt) {
    int row = gt * 256 + jh;
    float a = vv[576 + row] + Wihd[row * 257] * inp;
    for (int k = 0; k < 256; ++k) a += wxd[row * 256 + k] * (ctxacc[(size_t)b * 257 + k] * den);
    for (int k = 0; k < 256; ++k) a += Whhd[row * 256 + k] * hfin[b * 256 + k];
    gg[gt] = a;
  }
  float cn = sigf(gg[1]) * ccfin[b * 256 + jh] + sigf(gg[0]) * tanh_(gg[2]);
  float hn = sigf(gg[3]) * tanh_(cn);
  if (fabsf(hn - h1d[b * 256 + jh]) > 1e-4f) dout[3] = 2e3f;
}

// ---------------- launch ----------------
extern "C" void kernel_launch(void* const* d_in, const int* in_sizes, int n_in,
                              void* d_out, int out_size, void* d_ws, size_t ws_size,
                              hipStream_t stream) {
  (void)in_sizes; (void)n_in; (void)out_size;
  float* dout = (float*)d_out;
  if (ws_size < WS_NEED) {   // report actual ws budget via absmax: 1e6 + MiB
    k_wsfail<<<1, 1, 0, stream>>>(dout, (float)(ws_size >> 20));
    return;
  }
  const float* src1 = (const float*)d_in[0];
  const float* src2 = (const float*)d_in[1];
  const float* Wc   = (const float*)d_in[2];
  const float* bc   = (const float*)d_in[3];
  const float* Wihe = (const float*)d_in[4];
  const float* Whhe = (const float*)d_in[5];
  const float* bihe = (const float*)d_in[6];
  const float* bhhe = (const float*)d_in[7];
  const float* Wfc  = (const float*)d_in[8];
  const float* bfc  = (const float*)d_in[9];
  const float* Wf2  = (const float*)d_in[10];
  const float* bf2  = (const float*)d_in[11];
  const float* Wa   = (const float*)d_in[12];
  const float* Wihd = (const float*)d_in[13];
  const float* Whhd = (const float*)d_in[14];
  const float* bihd = (const float*)d_in[15];
  const float* bhhd = (const float*)d_in[16];
  const float* Wo   = (const float*)d_in[17];
  const float* bo   = (const float*)d_in[18];

  char* ws = (char*)d_ws;
  f16*   xf    = (f16*)(ws + XF_OFF);
  f16*   outs  = (f16*)(ws + OUTS_OFF);
  float* eproj = (float*)(ws + EPROJ_OFF);
  float* hh    = (float*)(ws + HH_OFF);
  float* cc    = (float*)(ws + CC_OFF);
  float* wxd   = (float*)(ws + WXD_OFF);
  float* vv    = (float*)(ws + VV_OFF);
  f16*   ws67  = (f16*)(ws + WS67_OFF);
  f16*   xb    = (f16*)(ws + XB_OFF);
  float* zb    = (float*)(ws + ZERO_OFF);
  float* ctxacc   = zb;
  float* s_acc    = zb + CTX_CNT;
  float* pred_acc = s_acc + SAC_CNT;
  float* inp_buf  = pred_acc + PRD_CNT;
  float* cdump = (float*)(ws + DUMP_OFF);
  float* ccfin = (float*)(ws + DUMP_OFF + DUMP_ONE);
  float* hfin  = (float*)(ws + DUMP_OFF + 2 * DUMP_ONE);
  float* h1d   = (float*)(ws + DUMP_OFF + 3 * DUMP_ONE);

  k_zero<<<256, 256, 0, stream>>>(zb, ZERO_CNT);
  k_prep<<<8, 256, 0, stream>>>(Wfc, Wa, Wf2, bf2, bfc, bihd, bhhd, Wihd, vv);
  k_wxd<<<1024, 256, 0, stream>>>(Wihd, Wfc, wxd);
  k_wprep<<<96, 256, 0, stream>>>(Whhe, Wihe, bihe, bhhe, ws67, xb);
  k_xf<<<1024, 256, 0, stream>>>(src1, src2, Wc, bc, xf);
  k_enc<<<NBLK, 512, 0, stream>>>(Whhe, ws67, xb, xf, outs, hh, cc, cdump, hfin, ccfin);
  k_eproj<<<B_ * T_ / 4, 256, 0, stream>>>(outs, vv, eproj);
  k_decinit<<<1, 256, 0, stream>>>(outs, hh, Wa, vv, inp_buf, s_acc);
  for (int d = 0; d < TRG_; ++d) {
    k_attn<<<B_ * 16, 256, 0, stream>>>(d, eproj, outs, s_acc, ctxacc, pred_acc, inp_buf, dout, bo);
    k_cell<<<64, 512, 0, stream>>>(d, wxd, Whhd, Wihd, vv, ctxacc, inp_buf, hh, cc, s_acc, pred_acc, Wa, Wo);
    if (d == 0) k_copyh<<<64, 512, 0, stream>>>(hh + B_ * H_, h1d);
  }
  k_finish<<<1, 128, 0, stream>>>(pred_acc, bo, dout);

  // ---- self-checks (write sentinels into d_out only on mismatch) ----
  k_check_cell<<<128, 256, 0, stream>>>(wxd, Whhd, Wihd, vv, ctxacc, inp_buf, hfin, ccfin, h1d, dout);
  k_check_dec<<<128, 64, 0, stream>>>(outs, eproj, s_acc, ctxacc, inp_buf, hh, hfin, h1d, Wa, Wo, bo, vv, dout);
  k_check_mid<<<197, 256, 0, stream>>>(Wfc, Wa, Wf2, bf2, bfc, bihd, bhhd, Wihd, vv, wxd, outs, eproj, dout);
  k_check_enc<<<256, 256, 0, stream>>>(src1, src2, Wc, bc, Wihe, bihe, bhhe, Whhe, outs, cdump, hfin, ccfin, dout);
}

// Round 4
// 14544.882 us; speedup vs baseline: 1.0663x; 1.0663x over previous
//
#include <hip/hip_runtime.h>
#include <hip/hip_fp16.h>

typedef __attribute__((ext_vector_type(4))) float f32x4;
typedef _Float16 f16;
typedef __attribute__((ext_vector_type(4))) _Float16 f16x4;
typedef __attribute__((ext_vector_type(8))) _Float16 f16x8;

#define DEV static __device__ __forceinline__

constexpr int B_ = 128, T_ = 2048, H_ = 256, TRG_ = 24;
constexpr int NBLK = 8;   // encoder blocks, 16 batches each

// ---------------- workspace layout (total ~150 MiB) ----------------
constexpr size_t XF_OFF   = 0;                                   // x A-fragments [t][blk][bb][32] f16
constexpr size_t XF_BYTES = (size_t)T_ * NBLK * 16 * 32 * 2;     // 16 MiB
constexpr size_t OUTS_OFF = XF_OFF + XF_BYTES;
constexpr size_t OUTS_BYTES = (size_t)B_ * T_ * H_ * 2;          // 128 MiB f16
constexpr size_t EPROJ_OFF = OUTS_OFF + OUTS_BYTES;
constexpr size_t EPROJ_BYTES = (size_t)B_ * T_ * 4;              // 1 MiB
constexpr size_t HH_OFF = EPROJ_OFF + EPROJ_BYTES;               // ping-pong decoder h (buf0 = enc final)
constexpr size_t HH_BYTES = 2ull * B_ * H_ * 4;
constexpr size_t CC_OFF = HH_OFF + HH_BYTES;
constexpr size_t CC_BYTES = (size_t)B_ * H_ * 4;
constexpr size_t WXD_OFF = CC_OFF + CC_BYTES;                    // Wih_d[:,1:] @ Wfc  (1024x256) f32
constexpr size_t WXD_BYTES = 1024ull * 256 * 4;
constexpr size_t VV_OFF = WXD_OFF + WXD_BYTES;                   // v[256] v2[256] c0 c2 ... bdp[1024]@576
constexpr size_t VV_BYTES = 8192;
constexpr size_t W367_OFF = VV_OFF + VV_BYTES;                   // streamed enc weights ks3,6,7 (x2 copies)
constexpr size_t W367_BYTES = 2ull * 3 * 4096 * 16;              // 384 KiB
constexpr size_t XB_OFF = W367_OFF + W367_BYTES;                 // streamed x weights (x2 copies)
constexpr size_t XB_BYTES = 2ull * 4096 * 16;                    // 128 KiB
constexpr size_t ZERO_OFF = XB_OFF + XB_BYTES;
constexpr size_t CTX_CNT = 24ull * 128 * 257;   // ctxacc
constexpr size_t SAC_CNT = 25ull * 128;         // s_acc
constexpr size_t PRD_CNT = 24ull * 128;         // pred_acc
constexpr size_t INP_CNT = 25ull * 128;         // inp_buf
constexpr size_t ZERO_CNT = CTX_CNT + SAC_CNT + PRD_CNT + INP_CNT;
constexpr size_t WS_NEED = ZERO_OFF + ZERO_CNT * 4 + 1024;

// ---------------- helpers ----------------
DEV float sigf(float x)  { return 1.0f / (1.0f + __expf(-x)); }
DEV float tanh_(float x) { return 1.0f - 2.0f / (__expf(2.0f * x) + 1.0f); }

// ---------------- ws-too-small sentinel: absmax reports ws MiB ----------------
__global__ void k_wsfail(float* __restrict__ dout, float mb) { dout[0] = 1e6f + mb; }

// ---------------- zero scratch ----------------
__global__ void k_zero(float* __restrict__ p, size_t n) {
  size_t i = (size_t)blockIdx.x * blockDim.x + threadIdx.x;
  size_t s = (size_t)gridDim.x * blockDim.x;
  for (; i < n; i += s) p[i] = 0.f;
}

// ---------------- small precomputed vectors ----------------
// vv: [0,256) v = Wfc.T@Wa_e ; [256,512) v2 = Wfc.T@Wf2 ; [512] c0=bfc.Wa_e ; [513] c2=bfc.Wf2+bf2 ;
// [576,1600) bdp = bih_d+bhh_d + Wih_d[:,1:]@bfc
__global__ void k_prep(const float* __restrict__ Wfc, const float* __restrict__ Wa,
                       const float* __restrict__ Wf2, const float* __restrict__ bf2_,
                       const float* __restrict__ bfc, const float* __restrict__ bihd,
                       const float* __restrict__ bhhd, const float* __restrict__ Wihd,
                       float* __restrict__ vv) {
  const int blk = blockIdx.x, tid = threadIdx.x;
  if (blk == 0) {
    float a = 0; for (int h = 0; h < 256; ++h) a += Wfc[h * 256 + tid] * Wa[256 + h];
    vv[tid] = a;
  } else if (blk == 1) {
    float a = 0; for (int h = 0; h < 256; ++h) a += Wfc[h * 256 + tid] * Wf2[h];
    vv[256 + tid] = a;
  } else if (blk == 2) {
    if (tid == 0) { float a = 0; for (int h = 0; h < 256; ++h) a += bfc[h] * Wa[256 + h]; vv[512] = a; }
    if (tid == 1) { float a = bf2_[0]; for (int h = 0; h < 256; ++h) a += bfc[h] * Wf2[h]; vv[513] = a; }
  } else if (blk < 7) {
    int j = (blk - 3) * 256 + tid;
    float a = bihd[j] + bhhd[j];
    for (int h = 0; h < 256; ++h) a += Wihd[j * 257 + 1 + h] * bfc[h];
    vv[576 + j] = a;
  }
}

// Wxd[j][k] = sum_h Wih_d[j][1+h] * Wfc[h][k]  (64 blocks x 16 rows)
__global__ void k_wxd(const float* __restrict__ Wihd, const float* __restrict__ Wfc,
                      float* __restrict__ wxd) {
  __shared__ float sR[16][256];
  const int tid = threadIdx.x;
  for (int i = tid; i < 16 * 256; i += 256) {
    int r = i >> 8, h = i & 255;
    sR[r][h] = Wihd[(blockIdx.x * 16 + r) * 257 + 1 + h];
  }
  __syncthreads();
  const int k = tid;
  float a[16];
#pragma unroll
  for (int r = 0; r < 16; ++r) a[r] = 0.f;
  for (int h = 0; h < 256; ++h) {
    float wv = Wfc[h * 256 + k];
#pragma unroll
    for (int r = 0; r < 16; ++r) a[r] += sR[r][h] * wv;
  }
#pragma unroll
  for (int r = 0; r < 16; ++r) wxd[(blockIdx.x * 16 + r) * 256 + k] = a[r];
}

// ---------------- streamed encoder weight images (f16, MFMA B-fragment order) ----------------
// w367: [copy][{ks3,ks6,ks7}][frag=(w*2+p)*4+q][lane] x f16x8 ; xb: [copy][frag][lane] x f16x8
__global__ void k_wprep(const float* __restrict__ Whh, const float* __restrict__ Wih,
                        const float* __restrict__ bih, const float* __restrict__ bhh,
                        f16* __restrict__ w367, f16* __restrict__ xb) {
  int i = blockIdx.x * 256 + threadIdx.x;
  if (i < 12288) {
    int l = i & 63, f = (i >> 6) & 63, ksi = i >> 12;
    const int kss[3] = {3, 6, 7};
    int ks = kss[ksi];
    int q = f & 3, p = (f >> 2) & 1, w = f >> 3;
    int g = l >> 4, c16 = l & 15;
    int row = 256 * q + 16 * (w + 8 * p) + c16;
    f16x8 v;
#pragma unroll
    for (int jj = 0; jj < 8; ++jj) v[jj] = (f16)Whh[row * 256 + ks * 32 + 8 * g + jj];
    ((f16x8*)w367)[i] = v;
    ((f16x8*)w367)[i + 12288] = v;    // copy 1
  } else if (i < 16384) {
    int j = i - 12288;
    int l = j & 63, f = (j >> 6) & 63;
    int q = f & 3, p = (f >> 2) & 1, w = f >> 3;
    int g = l >> 4, c16 = l & 15;
    int row = 256 * q + 16 * (w + 8 * p) + c16;
    f16x8 v;
#pragma unroll
    for (int jj = 0; jj < 8; ++jj) {
      int k = 8 * g + jj;
      float val = (k < 16) ? Wih[row * 16 + k] : (k == 16 ? (bih[row] + bhh[row]) : 0.f);
      v[jj] = (f16)val;
    }
    ((f16x8*)xb)[j] = v;
    ((f16x8*)xb)[j + 4096] = v;       // copy 1
  }
}

// ---------------- x A-fragment prepass: xf[t*128+b][32] = [src1(15), sm, 1, 0...] f16 ----------
__global__ __launch_bounds__(256) void k_xf(const float* __restrict__ src1,
    const float* __restrict__ src2, const float* __restrict__ Wc, const float* __restrict__ bc,
    f16* __restrict__ xf) {
  int i = blockIdx.x * 256 + threadIdx.x;   // i = t*128 + b
  int t = i >> 7, b = i & 127;
  f16x8 v0, v1, v2, v3;
#pragma unroll
  for (int f = 0; f < 8; ++f)  v0[f] = (f16)src1[((size_t)b * T_ + t) * 15 + f];
#pragma unroll
  for (int f = 0; f < 7; ++f)  v1[f] = (f16)src1[((size_t)b * T_ + t) * 15 + 8 + f];
  float s = bc[0];
#pragma unroll
  for (int u = 0; u < 8; ++u) s += src2[((size_t)b * T_ + t) * 8 + u] * Wc[u];
  v1[7] = (f16)s;
  v2 = (f16x8){(f16)1.f, (f16)0.f, (f16)0.f, (f16)0.f, (f16)0.f, (f16)0.f, (f16)0.f, (f16)0.f};
  v3 = (f16x8){(f16)0.f, (f16)0.f, (f16)0.f, (f16)0.f, (f16)0.f, (f16)0.f, (f16)0.f, (f16)0.f};
  f16* o = xf + (size_t)i * 32;
  *(f16x8*)(o) = v0; *(f16x8*)(o + 8) = v1; *(f16x8*)(o + 16) = v2; *(f16x8*)(o + 24) = v3;
}

// ---------------- encoder: persistent fp16 MFMA; ks0-2 VGPR, ks4-5 LDS, ks3/6/7/x streamed ----
__global__ __launch_bounds__(512, 2) void k_enc(const float* __restrict__ Whh,
    const f16* __restrict__ w367, const f16* __restrict__ xb, const f16* __restrict__ xf,
    f16* __restrict__ outs, float* __restrict__ hh0, float* __restrict__ cc0) {
  const int blk = blockIdx.x, tid = threadIdx.x;
  const int w = tid >> 6, l = tid & 63, g = l >> 4, c16 = l & 15;
  __shared__ f16x8 Wl[8192];              // ks4,5 B-fragments: [(ksl*8+w)*2+p)*4+q][lane] = 128 KiB
  __shared__ __align__(16) f16 hbuf[2][16 * 260];   // ping-pong h[b][jh], stride 260

  // VGPR-resident weights ks0..2
  f16x8 wf[3][2][4];
#pragma unroll
  for (int ks = 0; ks < 3; ++ks)
#pragma unroll
    for (int p = 0; p < 2; ++p)
#pragma unroll
      for (int q = 0; q < 4; ++q) {
        const int row = 256 * q + 16 * (w + 8 * p) + c16;
        const float* s = Whh + row * 256 + ks * 32 + 8 * g;
        f16x8 v;
#pragma unroll
        for (int jj = 0; jj < 8; ++jj) v[jj] = (f16)s[jj];
        wf[ks][p][q] = v;
      }
  // LDS-resident weights ks4,5
#pragma unroll
  for (int ksl = 0; ksl < 2; ++ksl)
#pragma unroll
    for (int p = 0; p < 2; ++p)
#pragma unroll
      for (int q = 0; q < 4; ++q) {
        const int row = 256 * q + 16 * (w + 8 * p) + c16;
        const float* s = Whh + row * 256 + (4 + ksl) * 32 + 8 * g;
        f16x8 v;
#pragma unroll
        for (int jj = 0; jj < 8; ++jj) v[jj] = (f16)s[jj];
        Wl[((((ksl * 8 + w) * 2 + p) * 4 + q)) * 64 + l] = v;
      }
  for (int i = tid; i < 16 * 260; i += 512) hbuf[0][i] = (f16)0.f;
  __syncthreads();

  f32x4 cst[2];
  cst[0] = (f32x4){0.f, 0.f, 0.f, 0.f};
  cst[1] = (f32x4){0.f, 0.f, 0.f, 0.f};

  const f16x8* w367v = (const f16x8*)w367;
  const f16x8* xbv = (const f16x8*)xb;
  const int fb = w * 8;                       // fragment base for this wave

#define LDA(ks) ({ const f16* hp = hb + c16 * 260 + (ks) * 32 + 8 * g; \
                   f16x4 a0 = *(const f16x4*)hp; f16x4 a1 = *(const f16x4*)(hp + 4); \
                   f16x8 a; a[0]=a0[0];a[1]=a0[1];a[2]=a0[2];a[3]=a0[3]; \
                   a[4]=a1[0];a[5]=a1[1];a[6]=a1[2];a[7]=a1[3]; a; })
#define MF8(A, BB) \
  { _Pragma("unroll") for (int p = 0; p < 2; ++p) \
    _Pragma("unroll") for (int q = 0; q < 4; ++q) \
      acc[p][q] = __builtin_amdgcn_mfma_f32_16x16x32_f16((A), BB[p][q], acc[p][q], 0, 0, 0); }

  for (int t = 0; t < T_; ++t) {
    const int cp = t & 1;
    const f16x8* sxp = xbv + (size_t)cp * 4096;
    const f16x8* s3 = w367v + ((size_t)cp * 3 + 0) * 4096;
    const f16x8* s6 = w367v + ((size_t)cp * 3 + 1) * 4096;
    const f16x8* s7 = w367v + ((size_t)cp * 3 + 2) * 4096;
    const f16* hb = hbuf[cp];

    // stage x-B and ks3-B
    f16x8 st0[2][4], st1[2][4];
#pragma unroll
    for (int p = 0; p < 2; ++p)
#pragma unroll
      for (int q = 0; q < 4; ++q) st0[p][q] = sxp[(size_t)(fb + p * 4 + q) * 64 + l];
#pragma unroll
    for (int p = 0; p < 2; ++p)
#pragma unroll
      for (int q = 0; q < 4; ++q) st1[p][q] = s3[(size_t)(fb + p * 4 + q) * 64 + l];
    const f16x8 xa = *(const f16x8*)(xf + (((size_t)t * 8 + blk) * 16 + c16) * 32 + 8 * g);

    f32x4 acc[2][4];
#pragma unroll
    for (int p = 0; p < 2; ++p)
#pragma unroll
      for (int q = 0; q < 4; ++q) acc[p][q] = (f32x4){0.f, 0.f, 0.f, 0.f};

    // ks0-2 from VGPR (covers st0/st1 latency)
#pragma unroll
    for (int ks = 0; ks < 3; ++ks) { const f16x8 a = LDA(ks); MF8(a, wf[ks]); }
    // x-part (consume st0) then restage st0 <- ks6
    MF8(xa, st0);
#pragma unroll
    for (int p = 0; p < 2; ++p)
#pragma unroll
      for (int q = 0; q < 4; ++q) st0[p][q] = s6[(size_t)(fb + p * 4 + q) * 64 + l];
    // ks3 (consume st1) then restage st1 <- ks7
    { const f16x8 a = LDA(3); MF8(a, st1); }
#pragma unroll
    for (int p = 0; p < 2; ++p)
#pragma unroll
      for (int q = 0; q < 4; ++q) st1[p][q] = s7[(size_t)(fb + p * 4 + q) * 64 + l];
    // ks4,5 from LDS (covers st0/st1 latency)
    { const f16x8 a = LDA(4);
#pragma unroll
      for (int p = 0; p < 2; ++p)
#pragma unroll
        for (int q = 0; q < 4; ++q) {
          const f16x8 bb = Wl[(((0 * 8 + w) * 2 + p) * 4 + q) * 64 + l];
          acc[p][q] = __builtin_amdgcn_mfma_f32_16x16x32_f16(a, bb, acc[p][q], 0, 0, 0);
        } }
    { const f16x8 a = LDA(5);
#pragma unroll
      for (int p = 0; p < 2; ++p)
#pragma unroll
        for (int q = 0; q < 4; ++q) {
          const f16x8 bb = Wl[(((1 * 8 + w) * 2 + p) * 4 + q) * 64 + l];
          acc[p][q] = __builtin_amdgcn_mfma_f32_16x16x32_f16(a, bb, acc[p][q], 0, 0, 0);
        } }
    // ks6, ks7 (consume st0, st1)
    { const f16x8 a = LDA(6); MF8(a, st0); }
    { const f16x8 a = LDA(7); MF8(a, st1); }

    // epilogue: LSTM cell, write h into ping-pong buffer
    f16* hw = hbuf[cp ^ 1];
#pragma unroll
    for (int p = 0; p < 2; ++p) {
      const int jh = 16 * (w + 8 * p) + c16;
#pragma unroll
      for (int r = 0; r < 4; ++r) {
        const float iv = acc[p][0][r], fv = acc[p][1][r], gv = acc[p][2][r], ov = acc[p][3][r];
        const float cn = sigf(fv) * cst[p][r] + sigf(iv) * tanh_(gv);
        cst[p][r] = cn;
        const float hn = sigf(ov) * tanh_(cn);
        const int bl = 4 * g + r;
        hw[bl * 260 + jh] = (f16)hn;
        outs[((size_t)(blk * 16 + bl) * T_ + t) * H_ + jh] = (f16)hn;
        if (t == T_ - 1) {
          hh0[(blk * 16 + bl) * H_ + jh] = hn;
          cc0[(blk * 16 + bl) * H_ + jh] = cn;
        }
      }
    }
    __syncthreads();
  }
#undef LDA
#undef MF8
}

// ---------------- eproj = outs.v + c0 ----------------
__global__ void k_eproj(const f16* __restrict__ outs, const float* __restrict__ vv,
                        float* __restrict__ eproj) {
  __shared__ float sv[256];
  const int tid = threadIdx.x;
  sv[tid] = vv[tid];
  __syncthreads();
  const int wv = tid >> 6, l = tid & 63;
  const int flat = blockIdx.x * 4 + wv;     // b*T + t
  const f16* op = outs + (size_t)flat * H_ + l * 4;
  float sum = 0;
#pragma unroll
  for (int i = 0; i < 4; ++i) sum += (float)op[i] * sv[l * 4 + i];
  for (int off = 32; off > 0; off >>= 1) sum += __shfl_down(sum, off);
  if (l == 0) eproj[flat] = sum + vv[512];
}

// ---------------- decoder init: token + s0 ----------------
__global__ void k_decinit(const f16* __restrict__ outs, const float* __restrict__ hh,
                          const float* __restrict__ Wa, const float* __restrict__ vv,
                          float* __restrict__ inp_buf, float* __restrict__ s_acc) {
  int b = threadIdx.x;
  if (b >= B_) return;
  float tok = vv[513];
  const f16* op = outs + ((size_t)b * T_ + (T_ - 1)) * H_;
  for (int k = 0; k < H_; ++k) tok += (float)op[k] * vv[256 + k];
  float s0 = 0;
  for (int j = 0; j < H_; ++j) s0 += hh[b * H_ + j] * Wa[j];
  inp_buf[b] = tok;
  s_acc[b] = s0;
}

// ---------------- attention: ctx' = softmax(tanh(s+eproj)) @ outs ----------------
__global__ void k_attn(int d, const float* __restrict__ eproj, const f16* __restrict__ outs,
                       const float* __restrict__ s_acc, float* __restrict__ ctxacc,
                       const float* __restrict__ pred_acc, float* __restrict__ inp_buf,
                       float* __restrict__ dout, const float* __restrict__ bo) {
  const int b = blockIdx.x >> 4, ch = blockIdx.x & 15;
  const int k = threadIdx.x;
  if (d > 0 && ch == 0 && k == 0) {   // finalize previous step's prediction
    float pv = pred_acc[(d - 1) * B_ + b] + bo[0];
    inp_buf[d * B_ + b] = pv;
    dout[b * TRG_ + (d - 1)] = pv;
  }
  __shared__ float swt[128];
  const float s = s_acc[d * B_ + b];
  if (k < 128) {
    float e = eproj[b * T_ + ch * 128 + k];
    swt[k] = __expf(tanh_(s + e));   // tanh bounds energies -> exp safe without max-subtract
  }
  __syncthreads();
  float acc = 0.f;
  const f16* op = outs + ((size_t)b * T_ + ch * 128) * H_ + k;
#pragma unroll 4
  for (int tt = 0; tt < 128; ++tt) acc += swt[tt] * (float)op[tt * H_];
  atomicAdd(&ctxacc[((size_t)d * B_ + b) * 257 + k], acc);
  if (k == 0) {
    float sw = 0;
    for (int tt = 0; tt < 128; ++tt) sw += swt[tt];
    atomicAdd(&ctxacc[((size_t)d * B_ + b) * 257 + 256], sw);
  }
}

// ---------------- decoder LSTM cell (+ next s, pred partials) ----------------
__global__ __launch_bounds__(512) void k_cell(int d, const float* __restrict__ wxd,
    const float* __restrict__ Whhd, const float* __restrict__ Wihd, const float* __restrict__ vv,
    const float* __restrict__ ctxacc, const float* __restrict__ inp_buf,
    float* __restrict__ hh, float* __restrict__ cc,
    float* __restrict__ s_acc, float* __restrict__ pred_acc,
    const float* __restrict__ Wa, const float* __restrict__ Wo) {
  const int jb = blockIdx.x;               // hidden cols [4jb, 4jb+4)
  const int tid = threadIdx.x;
  const int rr = tid & 15, bb = tid >> 4;  // rr = gate*4+jsub, bb = 0..31
  __shared__ float sW[16][516];
  __shared__ float sX[32][516];
  __shared__ float sG[32][17];
  __shared__ float sden[32], sinp[32];
  __shared__ float scol0[16], sbias[16];
  const float* bdp = vv + 576;
  for (int idx = tid; idx < 16 * 512; idx += 512) {
    int r2 = idx >> 9, k2 = idx & 511;
    int row = 256 * (r2 >> 2) + 4 * jb + (r2 & 3);
    sW[r2][k2] = (k2 < 256) ? wxd[row * 256 + k2] : Whhd[row * 256 + (k2 - 256)];
  }
  if (tid < 16) {
    int row = 256 * (tid >> 2) + 4 * jb + (tid & 3);
    scol0[tid] = Wihd[row * 257];
    sbias[tid] = bdp[row];
  }
  const float* hh_r = hh + (d & 1) * B_ * H_;
  float* hh_w = hh + ((d + 1) & 1) * B_ * H_;
  for (int bc = 0; bc < 4; ++bc) {
    __syncthreads();
    if (tid < 32) {
      int b = bc * 32 + tid;
      sden[tid] = 1.0f / ctxacc[((size_t)d * B_ + b) * 257 + 256];
      sinp[tid] = inp_buf[d * B_ + b];
    }
    __syncthreads();
    for (int idx = tid; idx < 32 * 512; idx += 512) {
      int b2 = idx >> 9, k2 = idx & 511;
      int b = bc * 32 + b2;
      sX[b2][k2] = (k2 < 256) ? ctxacc[((size_t)d * B_ + b) * 257 + k2] * sden[b2]
                              : hh_r[b * 256 + (k2 - 256)];
    }
    __syncthreads();
    {
      float a = sbias[rr] + scol0[rr] * sinp[bb];
      const float* wr = sW[rr];
      const float* xr = sX[bb];
      for (int k4 = 0; k4 < 512; k4 += 4)
        a += wr[k4] * xr[k4] + wr[k4 + 1] * xr[k4 + 1] + wr[k4 + 2] * xr[k4 + 2] + wr[k4 + 3] * xr[k4 + 3];
      sG[bb][rr] = a;
    }
    __syncthreads();
    if (rr < 4) {
      int b = bc * 32 + bb;
      int jh = 4 * jb + rr;
      float iv = sG[bb][rr], fv = sG[bb][4 + rr], gv = sG[bb][8 + rr], ov = sG[bb][12 + rr];
      float cn = sigf(fv) * cc[b * H_ + jh] + sigf(iv) * tanh_(gv);
      cc[b * H_ + jh] = cn;
      float hn = sigf(ov) * tanh_(cn);
      hh_w[b * H_ + jh] = hn;
      atomicAdd(&s_acc[(d + 1) * B_ + b], hn * Wa[jh]);
      atomicAdd(&pred_acc[d * B_ + b], hn * Wo[jh]);
    }
  }
}

__global__ void k_finish(const float* __restrict__ pred_acc, const float* __restrict__ bo,
                         float* __restrict__ dout) {
  int b = threadIdx.x;
  if (b < B_) dout[b * TRG_ + (TRG_ - 1)] = pred_acc[(TRG_ - 1) * B_ + b] + bo[0];
}

// ---------------- launch ----------------
extern "C" void kernel_launch(void* const* d_in, const int* in_sizes, int n_in,
                              void* d_out, int out_size, void* d_ws, size_t ws_size,
                              hipStream_t stream) {
  (void)in_sizes; (void)n_in; (void)out_size;
  float* dout = (float*)d_out;
  if (ws_size < WS_NEED) {   // report actual ws budget via absmax: 1e6 + MiB
    k_wsfail<<<1, 1, 0, stream>>>(dout, (float)(ws_size >> 20));
    return;
  }
  const float* src1 = (const float*)d_in[0];
  const float* src2 = (const float*)d_in[1];
  const float* Wc   = (const float*)d_in[2];
  const float* bc   = (const float*)d_in[3];
  const float* Wihe = (const float*)d_in[4];
  const float* Whhe = (const float*)d_in[5];
  const float* bihe = (const float*)d_in[6];
  const float* bhhe = (const float*)d_in[7];
  const float* Wfc  = (const float*)d_in[8];
  const float* bfc  = (const float*)d_in[9];
  const float* Wf2  = (const float*)d_in[10];
  const float* bf2  = (const float*)d_in[11];
  const float* Wa   = (const float*)d_in[12];
  const float* Wihd = (const float*)d_in[13];
  const float* Whhd = (const float*)d_in[14];
  const float* bihd = (const float*)d_in[15];
  const float* bhhd = (const float*)d_in[16];
  const float* Wo   = (const float*)d_in[17];
  const float* bo   = (const float*)d_in[18];

  char* ws = (char*)d_ws;
  f16*   xf    = (f16*)(ws + XF_OFF);
  f16*   outs  = (f16*)(ws + OUTS_OFF);
  float* eproj = (float*)(ws + EPROJ_OFF);
  float* hh    = (float*)(ws + HH_OFF);
  float* cc    = (float*)(ws + CC_OFF);
  float* wxd   = (float*)(ws + WXD_OFF);
  float* vv    = (float*)(ws + VV_OFF);
  f16*   w367  = (f16*)(ws + W367_OFF);
  f16*   xb    = (f16*)(ws + XB_OFF);
  float* zb    = (float*)(ws + ZERO_OFF);
  float* ctxacc   = zb;
  float* s_acc    = zb + CTX_CNT;
  float* pred_acc = s_acc + SAC_CNT;
  float* inp_buf  = pred_acc + PRD_CNT;

  k_zero<<<256, 256, 0, stream>>>(zb, ZERO_CNT);
  k_prep<<<8, 256, 0, stream>>>(Wfc, Wa, Wf2, bf2, bfc, bihd, bhhd, Wihd, vv);
  k_wxd<<<64, 256, 0, stream>>>(Wihd, Wfc, wxd);
  k_wprep<<<64, 256, 0, stream>>>(Whhe, Wihe, bihe, bhhe, w367, xb);
  k_xf<<<1024, 256, 0, stream>>>(src1, src2, Wc, bc, xf);
  k_enc<<<NBLK, 512, 0, stream>>>(Whhe, w367, xb, xf, outs, hh, cc);
  k_eproj<<<B_ * T_ / 4, 256, 0, stream>>>(outs, vv, eproj);
  k_decinit<<<1, 256, 0, stream>>>(outs, hh, Wa, vv, inp_buf, s_acc);
  for (int d = 0; d < TRG_; ++d) {
    k_attn<<<B_ * 16, 256, 0, stream>>>(d, eproj, outs, s_acc, ctxacc, pred_acc, inp_buf, dout, bo);
    k_cell<<<64, 512, 0, stream>>>(d, wxd, Whhd, Wihd, vv, ctxacc, inp_buf, hh, cc, s_acc, pred_acc, Wa, Wo);
  }
  k_finish<<<1, 128, 0, stream>>>(pred_acc, bo, dout);
}